// Round 1
// baseline (187.522 us; speedup 1.0000x reference)
//
#include <hip/hip_runtime.h>

#define NROWS   256
#define NCOLS   256
#define PENALTY 0.1f

// One block per image. 16 waves/block; wave w owns rows [16w, 16w+15].
// Lane i owns columns [4i, 4i+3] via float4 (64 float4 per row).
// Vertical diffs: keep previous row in registers (each row read once,
// except the 15 wave-boundary rows, re-read by the neighboring wave).
// Horizontal cross-lane diff via __shfl_down (wave=64 on gfx950).
__global__ __launch_bounds__(1024) void gaau_kernel(const float* __restrict__ Y,
                                                    float* __restrict__ out) {
    const int b    = blockIdx.x;
    const int tid  = threadIdx.x;
    const int lane = tid & 63;
    const int wave = tid >> 6;              // 0..15

    const float4* img = (const float4*)(Y + (size_t)b * (NROWS * NCOLS));

    const int r0    = wave * 16;
    const int rlast = r0 + 15;                          // last owned row
    const int rend  = (rlast < NROWS - 1) ? rlast + 1   // also read boundary row
                                          : NROWS - 1;  // wave 15: stop at 255

    float area = 0.0f, grad = 0.0f;

    // Row r0 (owned): area + horizontal diffs
    float4 prev = img[r0 * 64 + lane];
    area += prev.x + prev.y + prev.z + prev.w;
    grad += fabsf(prev.x - prev.y) + fabsf(prev.y - prev.z) + fabsf(prev.z - prev.w);
    {
        float nx = __shfl_down(prev.x, 1, 64);
        if (lane < 63) grad += fabsf(prev.w - nx);
    }

    #pragma unroll 4
    for (int r = r0 + 1; r <= rend; ++r) {
        float4 cur = img[r * 64 + lane];
        // vertical diffs between row r-1 and row r (pair owned by this wave)
        grad += fabsf(prev.x - cur.x) + fabsf(prev.y - cur.y) +
                fabsf(prev.z - cur.z) + fabsf(prev.w - cur.w);
        if (r <= rlast) {   // wave-uniform branch
            // row r owned: area + horizontal diffs
            area += cur.x + cur.y + cur.z + cur.w;
            grad += fabsf(cur.x - cur.y) + fabsf(cur.y - cur.z) + fabsf(cur.z - cur.w);
            float nx = __shfl_down(cur.x, 1, 64);
            if (lane < 63) grad += fabsf(cur.w - nx);
        }
        prev = cur;
    }

    // Per-thread partial
    float val = area - PENALTY * grad;

    // Wave-level shuffle reduction (64 lanes)
    #pragma unroll
    for (int off = 32; off > 0; off >>= 1)
        val += __shfl_down(val, off, 64);

    __shared__ float sm[16];
    if (lane == 0) sm[wave] = val;
    __syncthreads();

    if (tid == 0) {
        float s = 0.0f;
        #pragma unroll
        for (int i = 0; i < 16; ++i) s += sm[i];
        out[b] = s;
    }
}

extern "C" void kernel_launch(void* const* d_in, const int* in_sizes, int n_in,
                              void* d_out, int out_size, void* d_ws, size_t ws_size,
                              hipStream_t stream) {
    const float* Y  = (const float*)d_in[0];
    float* out      = (float*)d_out;
    const int batch = in_sizes[0] / (NROWS * NCOLS);   // 512
    gaau_kernel<<<batch, 1024, 0, stream>>>(Y, out);
}

// Round 2
// 186.882 us; speedup vs baseline: 1.0034x; 1.0034x over previous
//
#include <hip/hip_runtime.h>

#define NROWS   256
#define NCOLS   256
#define PENALTY 0.1f

// One block per image (grid=512 = exactly 2 blocks/CU, one wave-round).
// 16 waves/block; wave w owns rows [16w, 16w+15]. Lane i owns cols [4i,4i+3]
// via float4. Horizontal boundary diff: scalar load of y[r][4i+4] (same cache
// line as neighbor lane's float4 -> L1 hit, no extra HBM, no cross-lane op).
// Lane 63 clamps to col 255 => |y-y| = 0, branch-free.
// Vertical diffs: previous row carried in registers.
__global__ __launch_bounds__(1024, 8) void gaau_kernel(const float* __restrict__ Y,
                                                       float* __restrict__ out) {
    const int tid  = threadIdx.x;
    const int lane = tid & 63;
    const int wave = tid >> 6;              // 0..15

    const float*  img  = Y + (size_t)blockIdx.x * (NROWS * NCOLS);
    const float4* img4 = (const float4*)img;

    const int r0   = wave * 16;
    const int ncol = min(4 * lane + 4, NCOLS - 1);   // clamped neighbor column

    float area = 0.0f, gradh = 0.0f, gradv = 0.0f;

    // Row r0: area + horizontal diffs
    float4 prev = img4[r0 * (NCOLS / 4) + lane];
    {
        float nx = img[r0 * NCOLS + ncol];
        area  += (prev.x + prev.y) + (prev.z + prev.w);
        gradh += (fabsf(prev.x - prev.y) + fabsf(prev.y - prev.z)) +
                 (fabsf(prev.z - prev.w) + fabsf(prev.w - nx));
    }

    #pragma unroll 5
    for (int k = 1; k < 16; ++k) {
        const int r = r0 + k;
        float4 cur = img4[r * (NCOLS / 4) + lane];
        float  nx  = img[r * NCOLS + ncol];
        gradv += (fabsf(prev.x - cur.x) + fabsf(prev.y - cur.y)) +
                 (fabsf(prev.z - cur.z) + fabsf(prev.w - cur.w));
        area  += (cur.x + cur.y) + (cur.z + cur.w);
        gradh += (fabsf(cur.x - cur.y) + fabsf(cur.y - cur.z)) +
                 (fabsf(cur.z - cur.w) + fabsf(cur.w - nx));
        prev = cur;
    }

    // Boundary row: vertical diff between row r0+15 and r0+16 (wave-uniform branch)
    if (wave < 15) {
        float4 cur = img4[(r0 + 16) * (NCOLS / 4) + lane];
        gradv += (fabsf(prev.x - cur.x) + fabsf(prev.y - cur.y)) +
                 (fabsf(prev.z - cur.z) + fabsf(prev.w - cur.w));
    }

    float val = area - PENALTY * (gradh + gradv);

    // Wave reduction (64 lanes) then 16-slot LDS reduction
    #pragma unroll
    for (int off = 32; off > 0; off >>= 1)
        val += __shfl_down(val, off, 64);

    __shared__ float sm[16];
    if (lane == 0) sm[wave] = val;
    __syncthreads();

    if (tid == 0) {
        float s = 0.0f;
        #pragma unroll
        for (int i = 0; i < 16; ++i) s += sm[i];
        out[blockIdx.x] = s;
    }
}

extern "C" void kernel_launch(void* const* d_in, const int* in_sizes, int n_in,
                              void* d_out, int out_size, void* d_ws, size_t ws_size,
                              hipStream_t stream) {
    const float* Y  = (const float*)d_in[0];
    float* out      = (float*)d_out;
    const int batch = in_sizes[0] / (NROWS * NCOLS);   // 512
    gaau_kernel<<<batch, 1024, 0, stream>>>(Y, out);
}